// Round 21
// baseline (195.802 us; speedup 1.0000x reference)
//
#include <hip/hip_runtime.h>
#include <math.h>

#define LSEQ   2048
#define DMODEL 1024
#define DINNER 2048
#define DSTATE 16
#define DTRANK 64
#define XCOLS  96   // dt_rank + 2*d_state
#define CL     16   // scan chunk length (r21: 32->16 for 4 waves/SIMD TLP)
#define NC     (LSEQ/CL)          // 128 chunks
#define SSTATE (DINNER*DSTATE)    // 32768 scalar recurrences

typedef __attribute__((ext_vector_type(8))) short bf16x8;
typedef __attribute__((ext_vector_type(4))) float f32x4;
typedef unsigned short ushort_t;
typedef unsigned int uint_t;

__device__ __forceinline__ float siluf(float v) { return v / (1.f + __expf(-v)); }

// RNE float -> bf16 bits (finite inputs)
__device__ __forceinline__ ushort_t f2bf(float f) {
    uint_t u = __float_as_uint(f);
    u += 0x7FFFu + ((u >> 16) & 1u);
    return (ushort_t)(u >> 16);
}
__device__ __forceinline__ float bf2f(ushort_t u) {
    return __uint_as_float((uint_t)u << 16);
}

__device__ __forceinline__ bf16x8 cvt8(float4 lo, float4 hi) {
    bf16x8 r;
    r[0] = (short)f2bf(lo.x); r[1] = (short)f2bf(lo.y);
    r[2] = (short)f2bf(lo.z); r[3] = (short)f2bf(lo.w);
    r[4] = (short)f2bf(hi.x); r[5] = (short)f2bf(hi.y);
    r[6] = (short)f2bf(hi.z); r[7] = (short)f2bf(hi.w);
    return r;
}

// ---------------------------------------------------------------------------
// fused f32 -> bf16 cast for 5 tensors + zero-fill of xdbl.
// ---------------------------------------------------------------------------
__global__ __launch_bounds__(256)
void cast6_kernel(const float* __restrict__ s0, ushort_t* __restrict__ d0, int c0,
                  const float* __restrict__ s1, ushort_t* __restrict__ d1, int c1,
                  const float* __restrict__ s2, ushort_t* __restrict__ d2, int c2,
                  const float* __restrict__ s3, ushort_t* __restrict__ d3, int c3,
                  const float* __restrict__ s4, ushort_t* __restrict__ d4, int c4,
                  float* __restrict__ z0, int cz)
{
    int i = (blockIdx.x * 256 + threadIdx.x) * 8;
    int tot = c0 + c1 + c2 + c3 + c4;
    if (i < tot) {
        const float* s; ushort_t* d;
        if (i < c0)                { s = s0 + i;                  d = d0 + i; }
        else if (i < c0+c1)        { s = s1 + (i-c0);             d = d1 + (i-c0); }
        else if (i < c0+c1+c2)     { s = s2 + (i-c0-c1);          d = d2 + (i-c0-c1); }
        else if (i < c0+c1+c2+c3)  { s = s3 + (i-c0-c1-c2);       d = d3 + (i-c0-c1-c2); }
        else                       { s = s4 + (i-c0-c1-c2-c3);    d = d4 + (i-c0-c1-c2-c3); }
        *(bf16x8*)d = cvt8(*(const float4*)s, *(const float4*)(s + 4));
    } else if (i < tot + cz) {
        float* z = z0 + (i - tot);
        *(float4*)z       = make_float4(0.f, 0.f, 0.f, 0.f);
        *(float4*)(z + 4) = make_float4(0.f, 0.f, 0.f, 0.f);
    }
}

// ---------------------------------------------------------------------------
// bf16 MFMA GEMM — r5 measured-best loop (2-phase dbuf, BK=32, vmcnt(4)).
// EPI=0: fp32 store to Cp = C + blockIdx.z*partStride (split-K, no atomics).
// EPI=1: in_proj fused epilogue — x-half -> bf16 Xb; z-half -> silu -> Gz.
// LDS per buf: [4 kb][128 row][8 elem] -> SQ_LDS_BANK_CONFLICT == 0.
// ---------------------------------------------------------------------------
__device__ __forceinline__ void stage_tile(const ushort_t* __restrict__ A,
                                           const ushort_t* __restrict__ B,
                                           ushort_t* As, ushort_t* Bs,
                                           int m0, int n0, int K, int k0, int tid)
{
#pragma unroll
    for (int j = 0; j < 2; j++) {
        const int c   = j * 256 + tid;   // 16B chunk index 0..511
        const int row = c & 127;
        const int kbi = c >> 7;          // 0..3
        __builtin_amdgcn_global_load_lds(
            (const __attribute__((address_space(1))) uint_t*)(A + (size_t)(m0 + row) * K + k0 + kbi * 8),
            (__attribute__((address_space(3))) uint_t*)((char*)As + c * 16), 16, 0, 0);
        __builtin_amdgcn_global_load_lds(
            (const __attribute__((address_space(1))) uint_t*)(B + (size_t)(n0 + row) * K + k0 + kbi * 8),
            (__attribute__((address_space(3))) uint_t*)((char*)Bs + c * 16), 16, 0, 0);
    }
}

template<int EPI, int SPLITK>
__global__ __launch_bounds__(256)
void gemm_bf16(const ushort_t* __restrict__ A,
               const ushort_t* __restrict__ B,
               float* __restrict__ C,
               ushort_t* __restrict__ Xb,
               ushort_t* __restrict__ Gz,
               int M, int N, int K, size_t partStride)
{
    __shared__ ushort_t As[2][4096];
    __shared__ ushort_t Bs[2][4096];

    const int tid  = threadIdx.x;
    const int wid  = tid >> 6;
    const int lane = tid & 63;
    const int m0 = blockIdx.x * 128;
    const int n0 = blockIdx.y * 128;
    const int kcnt  = K / SPLITK;
    const int kbase = (SPLITK > 1) ? blockIdx.z * kcnt : 0;
    const int NT = kcnt / 32;
    float* Cp = (EPI == 0) ? C + (size_t)blockIdx.z * partStride : C;
    const int wr = (wid >> 1) * 64;
    const int wc = (wid & 1) * 64;
    const int lr = lane & 15;
    const int kbq = lane >> 4;

    f32x4 acc[4][4];
#pragma unroll
    for (int m = 0; m < 4; m++)
#pragma unroll
        for (int n = 0; n < 4; n++)
            acc[m][n] = (f32x4){0.f, 0.f, 0.f, 0.f};

    stage_tile(A, B, As[0], Bs[0], m0, n0, K, kbase, tid);

    for (int t = 0; t < NT; t++) {
        const int cur = t & 1;
        if (t + 1 < NT) {
            stage_tile(A, B, As[cur ^ 1], Bs[cur ^ 1], m0, n0, K, kbase + (t + 1) * 32, tid);
            asm volatile("s_waitcnt vmcnt(4)" ::: "memory");
        } else {
            asm volatile("s_waitcnt vmcnt(0)" ::: "memory");
        }
        __builtin_amdgcn_s_barrier();
        __builtin_amdgcn_sched_barrier(0);

        bf16x8 af[4], bfr[4];
#pragma unroll
        for (int m = 0; m < 4; m++)
            af[m] = *(const bf16x8*)&As[cur][(kbq * 128 + wr + m * 16 + lr) * 8];
#pragma unroll
        for (int n = 0; n < 4; n++)
            bfr[n] = *(const bf16x8*)&Bs[cur][(kbq * 128 + wc + n * 16 + lr) * 8];
#pragma unroll
        for (int m = 0; m < 4; m++)
#pragma unroll
            for (int n = 0; n < 4; n++)
                acc[m][n] = __builtin_amdgcn_mfma_f32_16x16x32_bf16(af[m], bfr[n], acc[m][n], 0, 0, 0);

        __builtin_amdgcn_sched_barrier(0);
        __builtin_amdgcn_s_barrier();
    }

    const int er = (lane >> 4) * 4;
    const int ec = lane & 15;
    if (EPI == 0) {
#pragma unroll
        for (int m = 0; m < 4; m++) {
            const int grow = m0 + wr + m * 16 + er;
#pragma unroll
            for (int n = 0; n < 4; n++) {
                const int gcol = n0 + wc + n * 16 + ec;
#pragma unroll
                for (int r = 0; r < 4; r++)
                    Cp[(size_t)(grow + r) * N + gcol] = acc[m][n][r];
            }
        }
    } else {
        const bool xside = (n0 < DINNER);   // uniform per block
#pragma unroll
        for (int m = 0; m < 4; m++) {
            const int grow = m0 + wr + m * 16 + er;
#pragma unroll
            for (int n = 0; n < 4; n++) {
                const int gcol = n0 + wc + n * 16 + ec;
#pragma unroll
                for (int r = 0; r < 4; r++) {
                    float v = acc[m][n][r];
                    if (xside)
                        Xb[(size_t)(grow + r) * DINNER + gcol] = f2bf(v);
                    else
                        Gz[(size_t)(grow + r) * DINNER + (gcol - DINNER)] = f2bf(siluf(v));
                }
            }
        }
    }
}

// ---------------------------------------------------------------------------
// out = p0 + p1 (two fp32 partials), float4 per thread.
// ---------------------------------------------------------------------------
__global__ __launch_bounds__(256)
void add2_kernel(const float* __restrict__ p0, const float* __restrict__ p1,
                 float* __restrict__ out, int n)
{
    int i = (blockIdx.x * 256 + threadIdx.x) * 4;
    if (i >= n) return;
    float4 a = *(const float4*)(p0 + i);
    float4 b = *(const float4*)(p1 + i);
    *(float4*)(out + i) = make_float4(a.x + b.x, a.y + b.y, a.z + b.z, a.w + b.w);
}

// ---------------------------------------------------------------------------
// x_dbl GEMM: direct-fragment MFMA, split-K=16, fp32 atomics on 786 KB output.
// ---------------------------------------------------------------------------
__global__ __launch_bounds__(256)
void gemm_xdbl(const ushort_t* __restrict__ A,
               const ushort_t* __restrict__ B,
               float* __restrict__ Cout)
{
    const int tid = threadIdx.x, wid = tid >> 6, lane = tid & 63;
    const int m0 = blockIdx.x * 128;
    const int kbase = blockIdx.z * 128;
    const int wr = (wid >> 1) * 64;
    const int wc = (wid & 1) * 48;
    const int lr = lane & 15;
    const int kq = (lane >> 4) * 8;

    f32x4 acc[4][3];
#pragma unroll
    for (int m = 0; m < 4; m++)
#pragma unroll
        for (int n = 0; n < 3; n++)
            acc[m][n] = (f32x4){0.f, 0.f, 0.f, 0.f};

#pragma unroll
    for (int ks = 0; ks < 4; ks++) {
        const int k0 = kbase + ks * 32;
        bf16x8 af[4], bfr[3];
#pragma unroll
        for (int m = 0; m < 4; m++)
            af[m] = *(const bf16x8*)(A + (size_t)(m0 + wr + m * 16 + lr) * DINNER + k0 + kq);
#pragma unroll
        for (int n = 0; n < 3; n++)
            bfr[n] = *(const bf16x8*)(B + (size_t)(wc + n * 16 + lr) * DINNER + k0 + kq);
#pragma unroll
        for (int m = 0; m < 4; m++)
#pragma unroll
            for (int n = 0; n < 3; n++)
                acc[m][n] = __builtin_amdgcn_mfma_f32_16x16x32_bf16(af[m], bfr[n], acc[m][n], 0, 0, 0);
    }

    const int er = (lane >> 4) * 4;
    const int ec = lane & 15;
#pragma unroll
    for (int m = 0; m < 4; m++)
#pragma unroll
        for (int n = 0; n < 3; n++)
#pragma unroll
            for (int r = 0; r < 4; r++)
                atomicAdd(&Cout[(size_t)(m0 + wr + m * 16 + er + r) * XCOLS + wc + n * 16 + ec],
                          acc[m][n][r]);
}

// ---------------------------------------------------------------------------
// dt GEMM: dtmb = bf16(softplus(xdbl[:, :64] @ Wdtb^T + b_dt)), direct stores.
// ---------------------------------------------------------------------------
__global__ __launch_bounds__(256)
void gemm_dt(const float* __restrict__ Axd,
             const ushort_t* __restrict__ Bw,
             const float* __restrict__ bias,
             ushort_t* __restrict__ dtmb)
{
    const int tid = threadIdx.x, wid = tid >> 6, lane = tid & 63;
    const int m0 = blockIdx.x * 128;
    const int n0 = blockIdx.y * 128;
    const int wr = (wid >> 1) * 64;
    const int wc = (wid & 1) * 64;
    const int lr = lane & 15;
    const int kq = (lane >> 4) * 8;

    f32x4 acc[4][4];
#pragma unroll
    for (int m = 0; m < 4; m++)
#pragma unroll
        for (int n = 0; n < 4; n++)
            acc[m][n] = (f32x4){0.f, 0.f, 0.f, 0.f};

#pragma unroll
    for (int kk = 0; kk < 2; kk++) {
        bf16x8 af[4], bfr[4];
#pragma unroll
        for (int m = 0; m < 4; m++) {
            const float* p = Axd + (size_t)(m0 + wr + m * 16 + lr) * XCOLS + kk * 32 + kq;
            af[m] = cvt8(*(const float4*)p, *(const float4*)(p + 4));
        }
#pragma unroll
        for (int n = 0; n < 4; n++)
            bfr[n] = *(const bf16x8*)(Bw + (size_t)(n0 + wc + n * 16 + lr) * DTRANK + kk * 32 + kq);
#pragma unroll
        for (int m = 0; m < 4; m++)
#pragma unroll
            for (int n = 0; n < 4; n++)
                acc[m][n] = __builtin_amdgcn_mfma_f32_16x16x32_bf16(af[m], bfr[n], acc[m][n], 0, 0, 0);
    }

    const int er = (lane >> 4) * 4;
    const int ec = lane & 15;
#pragma unroll
    for (int m = 0; m < 4; m++)
#pragma unroll
        for (int n = 0; n < 4; n++) {
            const int gcol = n0 + wc + n * 16 + ec;
            const float bv = bias[gcol];
#pragma unroll
            for (int r = 0; r < 4; r++) {
                float c = acc[m][n][r] + bv;
                c = (c > 20.f) ? c : log1pf(__expf(c));
                dtmb[(size_t)(m0 + wr + m * 16 + er + r) * DINNER + gcol] = f2bf(c);
            }
        }
}

// ---------------------------------------------------------------------------
// Depthwise causal conv (width 4) + bias + SiLU, bf16 I/O, 8 channels/thread.
// ---------------------------------------------------------------------------
__global__ __launch_bounds__(256)
void conv_silu_kernel(const ushort_t* __restrict__ xinb,
                      const float* __restrict__ conv_w,
                      const float* __restrict__ conv_b,
                      ushort_t* __restrict__ xcb)
{
    const int idx8 = blockIdx.x * 256 + threadIdx.x;   // 8-channel group
    const int t  = idx8 / (DINNER / 8);
    const int d0 = (idx8 - t * (DINNER / 8)) * 8;
    if (t >= LSEQ) return;

    bf16x8 zv = {0, 0, 0, 0, 0, 0, 0, 0};
    bf16x8 xr[4];
#pragma unroll
    for (int j = 0; j < 4; j++) {
        const int tt = t - 3 + j;
        xr[j] = (tt >= 0) ? *(const bf16x8*)(xinb + (size_t)tt * DINNER + d0) : zv;
    }
    bf16x8 outv;
#pragma unroll
    for (int e = 0; e < 8; e++) {
        const int d = d0 + e;
        const float4 w = *(const float4*)(conv_w + d * 4);
        float acc = conv_b[d];
        acc = fmaf(w.x, bf2f((ushort_t)xr[0][e]), acc);
        acc = fmaf(w.y, bf2f((ushort_t)xr[1][e]), acc);
        acc = fmaf(w.z, bf2f((ushort_t)xr[2][e]), acc);
        acc = fmaf(w.w, bf2f((ushort_t)xr[3][e]), acc);
        outv[e] = (short)f2bf(siluf(acc));
    }
    *(bf16x8*)(xcb + (size_t)t * DINNER + d0) = outv;
}

// ---------------------------------------------------------------------------
// Chunked parallel selective scan, CL=16 (1024 blocks -> 4 waves/SIMD TLP).
// ---------------------------------------------------------------------------
__global__ __launch_bounds__(256)
void scan_phase1(const ushort_t* __restrict__ dtmb,
                 const float* __restrict__ xdbl,
                 const ushort_t* __restrict__ xcb,
                 const float* __restrict__ A_log,
                 float* __restrict__ Aprod, float* __restrict__ hend)
{
    __shared__ float Bs[CL][16];
    const int tid = threadIdx.x;
    const int d = blockIdx.x * 256 + tid;
    const int c = blockIdx.y;
    const int t0 = c * CL;

    if (tid < CL * 8) {   // stage B chunk tile: CL*16 = 256 floats, 2/thread
        int t = tid >> 3, n = (tid * 2) & 15;
        float2 v = *(const float2*)&xdbl[(size_t)(t0 + t) * XCOLS + DTRANK + n];
        Bs[t][n] = v.x; Bs[t][n + 1] = v.y;
    }

    float a[16];
#pragma unroll
    for (int q = 0; q < 4; q++) {
        f32x4 v = *(const f32x4*)&A_log[(size_t)d * DSTATE + q * 4];
#pragma unroll
        for (int j = 0; j < 4; j++) a[q * 4 + j] = -__expf(v[j]);
    }
    float h[16];
#pragma unroll
    for (int n = 0; n < 16; n++) h[n] = 0.f;
    float sdt = 0.f;

    __syncthreads();

    float dtv = bf2f(dtmb[(size_t)t0 * DINNER + d]);
    float xv  = bf2f(xcb[(size_t)t0 * DINNER + d]);
    for (int tt = 0; tt < CL; tt++) {
        int tn_ = t0 + ((tt + 1 < CL) ? tt + 1 : tt);
        float dtv_n = bf2f(dtmb[(size_t)tn_ * DINNER + d]);
        float xv_n  = bf2f(xcb[(size_t)tn_ * DINNER + d]);

        f32x4 Bq[4];
#pragma unroll
        for (int q = 0; q < 4; q++) Bq[q] = *(const f32x4*)&Bs[tt][q * 4];
        float dtx = dtv * xv;
        sdt += dtv;
#pragma unroll
        for (int n = 0; n < 16; n++) {
            float e = __expf(dtv * a[n]);
            h[n] = fmaf(e, h[n], dtx * Bq[n >> 2][n & 3]);
        }
        dtv = dtv_n; xv = xv_n;
    }

#pragma unroll
    for (int n = 0; n < 16; n++) {
        const size_t k = (size_t)c * SSTATE + (size_t)n * DINNER + d;
        hend[k]  = h[n];
        Aprod[k] = __expf(a[n] * sdt);
    }
}

__global__ __launch_bounds__(64)
void scan_phase2(const float* __restrict__ Aprod, float* __restrict__ hend)
{
    const int idx = blockIdx.x * 64 + threadIdx.x;   // chain id (512 blocks)
    float carry = 0.f;
#pragma unroll 8
    for (int c = 0; c < NC; c++) {
        const size_t k = (size_t)c * SSTATE + idx;
        float oh = hend[k];
        float oA = Aprod[k];
        hend[k] = carry;
        carry = fmaf(oA, carry, oh);
    }
}

__global__ __launch_bounds__(256)
void scan_phase3(const ushort_t* __restrict__ dtmb,
                 const float* __restrict__ xdbl,
                 const ushort_t* __restrict__ xcb,
                 const float* __restrict__ A_log,
                 const float* __restrict__ Dp,
                 const ushort_t* __restrict__ gz,
                 const float* __restrict__ hinit,
                 ushort_t* __restrict__ yb)
{
    __shared__ float Bs[CL][16];
    __shared__ float Cs[CL][16];
    const int tid = threadIdx.x;
    const int d = blockIdx.x * 256 + tid;
    const int c = blockIdx.y;
    const int t0 = c * CL;

    if (tid < CL * 8) {   // stage B and C: 2 * CL*16 floats; threads 0..127
        int r = tid & 63;
        int t = r >> 2, n = (r * 4) & 15;
        const float* src = &xdbl[(size_t)(t0 + t) * XCOLS + DTRANK + ((tid < 64) ? 0 : DSTATE) + n];
        float4 v = *(const float4*)src;
        float* dst = (tid < 64) ? &Bs[t][n] : &Cs[t][n];
        dst[0] = v.x; dst[1] = v.y; dst[2] = v.z; dst[3] = v.w;
    }

    float a[16];
#pragma unroll
    for (int q = 0; q < 4; q++) {
        f32x4 v = *(const f32x4*)&A_log[(size_t)d * DSTATE + q * 4];
#pragma unroll
        for (int j = 0; j < 4; j++) a[q * 4 + j] = -__expf(v[j]);
    }
    const float Dv = Dp[d];
    float h[16];
#pragma unroll
    for (int n = 0; n < 16; n++)
        h[n] = hinit[(size_t)c * SSTATE + (size_t)n * DINNER + d];

    __syncthreads();

    float dtv = bf2f(dtmb[(size_t)t0 * DINNER + d]);
    float xv  = bf2f(xcb[(size_t)t0 * DINNER + d]);
    for (int tt = 0; tt < CL; tt++) {
        const int t = t0 + tt;
        int tn_ = t0 + ((tt + 1 < CL) ? tt + 1 : tt);
        float dtv_n = bf2f(dtmb[(size_t)tn_ * DINNER + d]);
        float xv_n  = bf2f(xcb[(size_t)tn_ * DINNER + d]);
        float gzv   = bf2f(gz[(size_t)t * DINNER + d]);

        f32x4 Bq[4], Cq[4];
#pragma unroll
        for (int q = 0; q < 4; q++) {
            Bq[q] = *(const f32x4*)&Bs[tt][q * 4];
            Cq[q] = *(const f32x4*)&Cs[tt][q * 4];
        }
        float dtx = dtv * xv;
        float y = 0.f;
#pragma unroll
        for (int n = 0; n < 16; n++) {
            float e = __expf(dtv * a[n]);
            h[n] = fmaf(e, h[n], dtx * Bq[n >> 2][n & 3]);
            y = fmaf(h[n], Cq[n >> 2][n & 3], y);
        }
        yb[(size_t)t * DINNER + d] = f2bf((y + Dv * xv) * gzv);
        dtv = dtv_n; xv = xv_n;
    }
}

// ---------------------------------------------------------------------------
extern "C" void kernel_launch(void* const* d_in, const int* in_sizes, int n_in,
                              void* d_out, int out_size, void* d_ws, size_t ws_size,
                              hipStream_t stream)
{
    const float* x      = (const float*)d_in[0];
    const float* W_in   = (const float*)d_in[1];
    const float* conv_w = (const float*)d_in[2];
    const float* conv_b = (const float*)d_in[3];
    const float* W_x    = (const float*)d_in[4];
    const float* W_dt   = (const float*)d_in[5];
    const float* b_dt   = (const float*)d_in[6];
    const float* A_log  = (const float*)d_in[7];
    const float* D_par  = (const float*)d_in[8];
    const float* W_out  = (const float*)d_in[9];
    float* out = (float*)d_out;
    float* ws  = (float*)d_ws;

    // fp32 region
    float* xdbl  = ws;                                    // 196608
    float* Aprod = xdbl + (size_t)LSEQ * XCOLS;           // NC*SSTATE = 4M
    float* hend  = Aprod + (size_t)NC * SSTATE;           // 4M
    // bf16 region
    ushort_t* xb   = (ushort_t*)(hend + (size_t)NC * SSTATE); // 2M  (x cast)
    ushort_t* Wib  = xb   + (size_t)LSEQ * DMODEL;            // 4M  (W_in)
    ushort_t* Wob  = Wib  + (size_t)(2*DINNER) * DMODEL;      // 2M  (W_out)
    ushort_t* Wxb  = Wob  + (size_t)DMODEL * DINNER;          // 196608
    ushort_t* Wdtb = Wxb  + (size_t)XCOLS * DINNER;           // 131072
    ushort_t* xinb = Wdtb + (size_t)DINNER * DTRANK;          // 4M  (pre-conv x)
    ushort_t* gz   = xinb + (size_t)LSEQ * DINNER;            // 4M  (silu(z))
    ushort_t* xcb  = gz   + (size_t)LSEQ * DINNER;            // 4M  (x_conv)
    ushort_t* dtmb = xcb  + (size_t)LSEQ * DINNER;            // 4M  (dt)
    ushort_t* yb   = dtmb + (size_t)LSEQ * DINNER;            // 4M  (y)
    // out_proj SK2 fp32 partials: 2 x 8 MB over xcb+dtmb (dead after phase3).
    float* outp = (float*)xcb;

    // 0. fused casts to bf16 (x, W_in, W_out, W_x, W_dt) + zero xdbl
    {
        int c0 = LSEQ * DMODEL, c1 = 2 * DINNER * DMODEL, c2 = DMODEL * DINNER;
        int c3 = XCOLS * DINNER, c4 = DINNER * DTRANK;
        int cz = LSEQ * XCOLS;
        int total = c0 + c1 + c2 + c3 + c4 + cz;
        hipLaunchKernelGGL(cast6_kernel, dim3((total / 8 + 255) / 256), dim3(256), 0, stream,
                           x, xb, c0, W_in, Wib, c1, W_out, Wob, c2,
                           W_x, Wxb, c3, W_dt, Wdtb, c4, xdbl, cz);
    }

    // 1. in_proj (2048 x 4096), fused epilogue: x-half -> xinb, z-half -> gz
    hipLaunchKernelGGL((gemm_bf16<1,1>), dim3(LSEQ/128, (2*DINNER)/128), dim3(256), 0, stream,
                       xb, Wib, (float*)nullptr, xinb, gz, LSEQ, 2*DINNER, DMODEL, (size_t)0);

    // 2. depthwise conv + SiLU (bf16, vectorized 8 ch/thread)
    hipLaunchKernelGGL(conv_silu_kernel, dim3((LSEQ*DINNER/8)/256), dim3(256), 0, stream,
                       xinb, conv_w, conv_b, xcb);

    // 3. x_dbl = xc @ W_x^T  (2048 x 96), direct-fragment MFMA, split-K=16
    hipLaunchKernelGGL(gemm_xdbl, dim3(LSEQ/128, 1, 16), dim3(256), 0, stream,
                       xcb, Wxb, xdbl);

    // 4. dt = softplus(x_dbl[:, :64] @ W_dt^T + b_dt) -> bf16
    hipLaunchKernelGGL(gemm_dt, dim3(LSEQ/128, DINNER/128), dim3(256), 0, stream,
                       xdbl, Wdtb, b_dt, dtmb);

    // 5. chunked parallel scan, CL=16 (1024-block phases, 4 waves/SIMD)
    hipLaunchKernelGGL(scan_phase1, dim3(DINNER/256, NC), dim3(256), 0, stream,
                       dtmb, xdbl, xcb, A_log, Aprod, hend);
    hipLaunchKernelGGL(scan_phase2, dim3(SSTATE/64), dim3(64), 0, stream,
                       Aprod, hend);
    hipLaunchKernelGGL(scan_phase3, dim3(DINNER/256, NC), dim3(256), 0, stream,
                       dtmb, xdbl, xcb, A_log, D_par, gz, hend, yb);

    // 6. out = y @ W_out^T  (2048 x 1024): SK2 partials + add2
    hipLaunchKernelGGL((gemm_bf16<0,2>), dim3(LSEQ/128, DMODEL/128, 2), dim3(256), 0, stream,
                       yb, Wob, outp, (ushort_t*)nullptr, (ushort_t*)nullptr,
                       LSEQ, DMODEL, DINNER, (size_t)(LSEQ*DMODEL));
    hipLaunchKernelGGL(add2_kernel, dim3((LSEQ*DMODEL/4)/256), dim3(256), 0, stream,
                       outp, outp + (size_t)LSEQ*DMODEL, out, LSEQ*DMODEL);
}

// Round 22
// 192.163 us; speedup vs baseline: 1.0189x; 1.0189x over previous
//
#include <hip/hip_runtime.h>
#include <math.h>

#define LSEQ   2048
#define DMODEL 1024
#define DINNER 2048
#define DSTATE 16
#define DTRANK 64
#define XCOLS  96   // dt_rank + 2*d_state
#define CL     32   // scan chunk length (r20 measured-best)
#define NC     (LSEQ/CL)          // 64 chunks
#define SSTATE (DINNER*DSTATE)    // 32768 scalar recurrences

typedef __attribute__((ext_vector_type(8))) short bf16x8;
typedef __attribute__((ext_vector_type(4))) float f32x4;
typedef unsigned short ushort_t;
typedef unsigned int uint_t;

__device__ __forceinline__ float siluf(float v) { return v / (1.f + __expf(-v)); }

// RNE float -> bf16 bits (finite inputs)
__device__ __forceinline__ ushort_t f2bf(float f) {
    uint_t u = __float_as_uint(f);
    u += 0x7FFFu + ((u >> 16) & 1u);
    return (ushort_t)(u >> 16);
}
__device__ __forceinline__ float bf2f(ushort_t u) {
    return __uint_as_float((uint_t)u << 16);
}

__device__ __forceinline__ bf16x8 cvt8(float4 lo, float4 hi) {
    bf16x8 r;
    r[0] = (short)f2bf(lo.x); r[1] = (short)f2bf(lo.y);
    r[2] = (short)f2bf(lo.z); r[3] = (short)f2bf(lo.w);
    r[4] = (short)f2bf(hi.x); r[5] = (short)f2bf(hi.y);
    r[6] = (short)f2bf(hi.z); r[7] = (short)f2bf(hi.w);
    return r;
}

// ---------------------------------------------------------------------------
// fused f32 -> bf16 cast for 5 tensors + zero-fill of xdbl.
// ---------------------------------------------------------------------------
__global__ __launch_bounds__(256)
void cast6_kernel(const float* __restrict__ s0, ushort_t* __restrict__ d0, int c0,
                  const float* __restrict__ s1, ushort_t* __restrict__ d1, int c1,
                  const float* __restrict__ s2, ushort_t* __restrict__ d2, int c2,
                  const float* __restrict__ s3, ushort_t* __restrict__ d3, int c3,
                  const float* __restrict__ s4, ushort_t* __restrict__ d4, int c4,
                  float* __restrict__ z0, int cz)
{
    int i = (blockIdx.x * 256 + threadIdx.x) * 8;
    int tot = c0 + c1 + c2 + c3 + c4;
    if (i < tot) {
        const float* s; ushort_t* d;
        if (i < c0)                { s = s0 + i;                  d = d0 + i; }
        else if (i < c0+c1)        { s = s1 + (i-c0);             d = d1 + (i-c0); }
        else if (i < c0+c1+c2)     { s = s2 + (i-c0-c1);          d = d2 + (i-c0-c1); }
        else if (i < c0+c1+c2+c3)  { s = s3 + (i-c0-c1-c2);       d = d3 + (i-c0-c1-c2); }
        else                       { s = s4 + (i-c0-c1-c2-c3);    d = d4 + (i-c0-c1-c2-c3); }
        *(bf16x8*)d = cvt8(*(const float4*)s, *(const float4*)(s + 4));
    } else if (i < tot + cz) {
        float* z = z0 + (i - tot);
        *(float4*)z       = make_float4(0.f, 0.f, 0.f, 0.f);
        *(float4*)(z + 4) = make_float4(0.f, 0.f, 0.f, 0.f);
    }
}

// ---------------------------------------------------------------------------
// bf16 MFMA GEMM — r5 measured-best loop (2-phase dbuf, BK=32, vmcnt(4)).
// EPI=0: fp32 store to Cp = C + blockIdx.z*partStride (split-K, no atomics).
// EPI=1: in_proj fused epilogue — x-half -> bf16 Xb; z-half -> silu -> Gz.
// LDS per buf: [4 kb][128 row][8 elem] -> SQ_LDS_BANK_CONFLICT == 0.
// ---------------------------------------------------------------------------
__device__ __forceinline__ void stage_tile(const ushort_t* __restrict__ A,
                                           const ushort_t* __restrict__ B,
                                           ushort_t* As, ushort_t* Bs,
                                           int m0, int n0, int K, int k0, int tid)
{
#pragma unroll
    for (int j = 0; j < 2; j++) {
        const int c   = j * 256 + tid;   // 16B chunk index 0..511
        const int row = c & 127;
        const int kbi = c >> 7;          // 0..3
        __builtin_amdgcn_global_load_lds(
            (const __attribute__((address_space(1))) uint_t*)(A + (size_t)(m0 + row) * K + k0 + kbi * 8),
            (__attribute__((address_space(3))) uint_t*)((char*)As + c * 16), 16, 0, 0);
        __builtin_amdgcn_global_load_lds(
            (const __attribute__((address_space(1))) uint_t*)(B + (size_t)(n0 + row) * K + k0 + kbi * 8),
            (__attribute__((address_space(3))) uint_t*)((char*)Bs + c * 16), 16, 0, 0);
    }
}

template<int EPI, int SPLITK>
__global__ __launch_bounds__(256)
void gemm_bf16(const ushort_t* __restrict__ A,
               const ushort_t* __restrict__ B,
               float* __restrict__ C,
               ushort_t* __restrict__ Xb,
               ushort_t* __restrict__ Gz,
               int M, int N, int K, size_t partStride)
{
    __shared__ ushort_t As[2][4096];
    __shared__ ushort_t Bs[2][4096];

    const int tid  = threadIdx.x;
    const int wid  = tid >> 6;
    const int lane = tid & 63;
    const int m0 = blockIdx.x * 128;
    const int n0 = blockIdx.y * 128;
    const int kcnt  = K / SPLITK;
    const int kbase = (SPLITK > 1) ? blockIdx.z * kcnt : 0;
    const int NT = kcnt / 32;
    float* Cp = (EPI == 0) ? C + (size_t)blockIdx.z * partStride : C;
    const int wr = (wid >> 1) * 64;
    const int wc = (wid & 1) * 64;
    const int lr = lane & 15;
    const int kbq = lane >> 4;

    f32x4 acc[4][4];
#pragma unroll
    for (int m = 0; m < 4; m++)
#pragma unroll
        for (int n = 0; n < 4; n++)
            acc[m][n] = (f32x4){0.f, 0.f, 0.f, 0.f};

    stage_tile(A, B, As[0], Bs[0], m0, n0, K, kbase, tid);

    for (int t = 0; t < NT; t++) {
        const int cur = t & 1;
        if (t + 1 < NT) {
            stage_tile(A, B, As[cur ^ 1], Bs[cur ^ 1], m0, n0, K, kbase + (t + 1) * 32, tid);
            asm volatile("s_waitcnt vmcnt(4)" ::: "memory");
        } else {
            asm volatile("s_waitcnt vmcnt(0)" ::: "memory");
        }
        __builtin_amdgcn_s_barrier();
        __builtin_amdgcn_sched_barrier(0);

        bf16x8 af[4], bfr[4];
#pragma unroll
        for (int m = 0; m < 4; m++)
            af[m] = *(const bf16x8*)&As[cur][(kbq * 128 + wr + m * 16 + lr) * 8];
#pragma unroll
        for (int n = 0; n < 4; n++)
            bfr[n] = *(const bf16x8*)&Bs[cur][(kbq * 128 + wc + n * 16 + lr) * 8];
#pragma unroll
        for (int m = 0; m < 4; m++)
#pragma unroll
            for (int n = 0; n < 4; n++)
                acc[m][n] = __builtin_amdgcn_mfma_f32_16x16x32_bf16(af[m], bfr[n], acc[m][n], 0, 0, 0);

        __builtin_amdgcn_sched_barrier(0);
        __builtin_amdgcn_s_barrier();
    }

    const int er = (lane >> 4) * 4;
    const int ec = lane & 15;
    if (EPI == 0) {
#pragma unroll
        for (int m = 0; m < 4; m++) {
            const int grow = m0 + wr + m * 16 + er;
#pragma unroll
            for (int n = 0; n < 4; n++) {
                const int gcol = n0 + wc + n * 16 + ec;
#pragma unroll
                for (int r = 0; r < 4; r++)
                    Cp[(size_t)(grow + r) * N + gcol] = acc[m][n][r];
            }
        }
    } else {
        const bool xside = (n0 < DINNER);   // uniform per block
#pragma unroll
        for (int m = 0; m < 4; m++) {
            const int grow = m0 + wr + m * 16 + er;
#pragma unroll
            for (int n = 0; n < 4; n++) {
                const int gcol = n0 + wc + n * 16 + ec;
#pragma unroll
                for (int r = 0; r < 4; r++) {
                    float v = acc[m][n][r];
                    if (xside)
                        Xb[(size_t)(grow + r) * DINNER + gcol] = f2bf(v);
                    else
                        Gz[(size_t)(grow + r) * DINNER + (gcol - DINNER)] = f2bf(siluf(v));
                }
            }
        }
    }
}

// ---------------------------------------------------------------------------
// out = p0 + p1 (two fp32 partials), float4 per thread.
// ---------------------------------------------------------------------------
__global__ __launch_bounds__(256)
void add2_kernel(const float* __restrict__ p0, const float* __restrict__ p1,
                 float* __restrict__ out, int n)
{
    int i = (blockIdx.x * 256 + threadIdx.x) * 4;
    if (i >= n) return;
    float4 a = *(const float4*)(p0 + i);
    float4 b = *(const float4*)(p1 + i);
    *(float4*)(out + i) = make_float4(a.x + b.x, a.y + b.y, a.z + b.z, a.w + b.w);
}

// ---------------------------------------------------------------------------
// x_dbl GEMM: direct-fragment MFMA, split-K=16, fp32 atomics on 786 KB output.
// ---------------------------------------------------------------------------
__global__ __launch_bounds__(256)
void gemm_xdbl(const ushort_t* __restrict__ A,
               const ushort_t* __restrict__ B,
               float* __restrict__ Cout)
{
    const int tid = threadIdx.x, wid = tid >> 6, lane = tid & 63;
    const int m0 = blockIdx.x * 128;
    const int kbase = blockIdx.z * 128;
    const int wr = (wid >> 1) * 64;
    const int wc = (wid & 1) * 48;
    const int lr = lane & 15;
    const int kq = (lane >> 4) * 8;

    f32x4 acc[4][3];
#pragma unroll
    for (int m = 0; m < 4; m++)
#pragma unroll
        for (int n = 0; n < 3; n++)
            acc[m][n] = (f32x4){0.f, 0.f, 0.f, 0.f};

#pragma unroll
    for (int ks = 0; ks < 4; ks++) {
        const int k0 = kbase + ks * 32;
        bf16x8 af[4], bfr[3];
#pragma unroll
        for (int m = 0; m < 4; m++)
            af[m] = *(const bf16x8*)(A + (size_t)(m0 + wr + m * 16 + lr) * DINNER + k0 + kq);
#pragma unroll
        for (int n = 0; n < 3; n++)
            bfr[n] = *(const bf16x8*)(B + (size_t)(wc + n * 16 + lr) * DINNER + k0 + kq);
#pragma unroll
        for (int m = 0; m < 4; m++)
#pragma unroll
            for (int n = 0; n < 3; n++)
                acc[m][n] = __builtin_amdgcn_mfma_f32_16x16x32_bf16(af[m], bfr[n], acc[m][n], 0, 0, 0);
    }

    const int er = (lane >> 4) * 4;
    const int ec = lane & 15;
#pragma unroll
    for (int m = 0; m < 4; m++)
#pragma unroll
        for (int n = 0; n < 3; n++)
#pragma unroll
            for (int r = 0; r < 4; r++)
                atomicAdd(&Cout[(size_t)(m0 + wr + m * 16 + er + r) * XCOLS + wc + n * 16 + ec],
                          acc[m][n][r]);
}

// ---------------------------------------------------------------------------
// dt GEMM: dtmb = bf16(softplus(xdbl[:, :64] @ Wdtb^T + b_dt)), direct stores.
// ---------------------------------------------------------------------------
__global__ __launch_bounds__(256)
void gemm_dt(const float* __restrict__ Axd,
             const ushort_t* __restrict__ Bw,
             const float* __restrict__ bias,
             ushort_t* __restrict__ dtmb)
{
    const int tid = threadIdx.x, wid = tid >> 6, lane = tid & 63;
    const int m0 = blockIdx.x * 128;
    const int n0 = blockIdx.y * 128;
    const int wr = (wid >> 1) * 64;
    const int wc = (wid & 1) * 64;
    const int lr = lane & 15;
    const int kq = (lane >> 4) * 8;

    f32x4 acc[4][4];
#pragma unroll
    for (int m = 0; m < 4; m++)
#pragma unroll
        for (int n = 0; n < 4; n++)
            acc[m][n] = (f32x4){0.f, 0.f, 0.f, 0.f};

#pragma unroll
    for (int kk = 0; kk < 2; kk++) {
        bf16x8 af[4], bfr[4];
#pragma unroll
        for (int m = 0; m < 4; m++) {
            const float* p = Axd + (size_t)(m0 + wr + m * 16 + lr) * XCOLS + kk * 32 + kq;
            af[m] = cvt8(*(const float4*)p, *(const float4*)(p + 4));
        }
#pragma unroll
        for (int n = 0; n < 4; n++)
            bfr[n] = *(const bf16x8*)(Bw + (size_t)(n0 + wc + n * 16 + lr) * DTRANK + kk * 32 + kq);
#pragma unroll
        for (int m = 0; m < 4; m++)
#pragma unroll
            for (int n = 0; n < 4; n++)
                acc[m][n] = __builtin_amdgcn_mfma_f32_16x16x32_bf16(af[m], bfr[n], acc[m][n], 0, 0, 0);
    }

    const int er = (lane >> 4) * 4;
    const int ec = lane & 15;
#pragma unroll
    for (int m = 0; m < 4; m++)
#pragma unroll
        for (int n = 0; n < 4; n++) {
            const int gcol = n0 + wc + n * 16 + ec;
            const float bv = bias[gcol];
#pragma unroll
            for (int r = 0; r < 4; r++) {
                float c = acc[m][n][r] + bv;
                c = (c > 20.f) ? c : log1pf(__expf(c));
                dtmb[(size_t)(m0 + wr + m * 16 + er + r) * DINNER + gcol] = f2bf(c);
            }
        }
}

// ---------------------------------------------------------------------------
// Depthwise causal conv (width 4) + bias + SiLU, bf16 I/O, 8 channels/thread.
// ---------------------------------------------------------------------------
__global__ __launch_bounds__(256)
void conv_silu_kernel(const ushort_t* __restrict__ xinb,
                      const float* __restrict__ conv_w,
                      const float* __restrict__ conv_b,
                      ushort_t* __restrict__ xcb)
{
    const int idx8 = blockIdx.x * 256 + threadIdx.x;   // 8-channel group
    const int t  = idx8 / (DINNER / 8);
    const int d0 = (idx8 - t * (DINNER / 8)) * 8;
    if (t >= LSEQ) return;

    bf16x8 zv = {0, 0, 0, 0, 0, 0, 0, 0};
    bf16x8 xr[4];
#pragma unroll
    for (int j = 0; j < 4; j++) {
        const int tt = t - 3 + j;
        xr[j] = (tt >= 0) ? *(const bf16x8*)(xinb + (size_t)tt * DINNER + d0) : zv;
    }
    bf16x8 outv;
#pragma unroll
    for (int e = 0; e < 8; e++) {
        const int d = d0 + e;
        const float4 w = *(const float4*)(conv_w + d * 4);
        float acc = conv_b[d];
        acc = fmaf(w.x, bf2f((ushort_t)xr[0][e]), acc);
        acc = fmaf(w.y, bf2f((ushort_t)xr[1][e]), acc);
        acc = fmaf(w.z, bf2f((ushort_t)xr[2][e]), acc);
        acc = fmaf(w.w, bf2f((ushort_t)xr[3][e]), acc);
        outv[e] = (short)f2bf(siluf(acc));
    }
    *(bf16x8*)(xcb + (size_t)t * DINNER + d0) = outv;
}

// ---------------------------------------------------------------------------
// Chunked parallel selective scan, CL=32 (r20 measured-best config).
// ---------------------------------------------------------------------------
__global__ __launch_bounds__(256)
void scan_phase1(const ushort_t* __restrict__ dtmb,
                 const float* __restrict__ xdbl,
                 const ushort_t* __restrict__ xcb,
                 const float* __restrict__ A_log,
                 float* __restrict__ Aprod, float* __restrict__ hend)
{
    __shared__ float Bs[CL][16];
    const int tid = threadIdx.x;
    const int d = blockIdx.x * 256 + tid;
    const int c = blockIdx.y;
    const int t0 = c * CL;

    {
        int t = tid >> 3, n = (tid * 2) & 15;
        float2 v = *(const float2*)&xdbl[(size_t)(t0 + t) * XCOLS + DTRANK + n];
        Bs[t][n] = v.x; Bs[t][n + 1] = v.y;
    }

    float a[16];
#pragma unroll
    for (int q = 0; q < 4; q++) {
        f32x4 v = *(const f32x4*)&A_log[(size_t)d * DSTATE + q * 4];
#pragma unroll
        for (int j = 0; j < 4; j++) a[q * 4 + j] = -__expf(v[j]);
    }
    float h[16];
#pragma unroll
    for (int n = 0; n < 16; n++) h[n] = 0.f;
    float sdt = 0.f;

    __syncthreads();

    float dtv = bf2f(dtmb[(size_t)t0 * DINNER + d]);
    float xv  = bf2f(xcb[(size_t)t0 * DINNER + d]);
    for (int tt = 0; tt < CL; tt++) {
        int tn_ = t0 + ((tt + 1 < CL) ? tt + 1 : tt);
        float dtv_n = bf2f(dtmb[(size_t)tn_ * DINNER + d]);
        float xv_n  = bf2f(xcb[(size_t)tn_ * DINNER + d]);

        f32x4 Bq[4];
#pragma unroll
        for (int q = 0; q < 4; q++) Bq[q] = *(const f32x4*)&Bs[tt][q * 4];
        float dtx = dtv * xv;
        sdt += dtv;
#pragma unroll
        for (int n = 0; n < 16; n++) {
            float e = __expf(dtv * a[n]);
            h[n] = fmaf(e, h[n], dtx * Bq[n >> 2][n & 3]);
        }
        dtv = dtv_n; xv = xv_n;
    }

#pragma unroll
    for (int n = 0; n < 16; n++) {
        const size_t k = (size_t)c * SSTATE + (size_t)n * DINNER + d;
        hend[k]  = h[n];
        Aprod[k] = __expf(a[n] * sdt);
    }
}

__global__ __launch_bounds__(64)
void scan_phase2(const float* __restrict__ Aprod, float* __restrict__ hend)
{
    const int idx = blockIdx.x * 64 + threadIdx.x;   // chain id (512 blocks)
    float carry = 0.f;
#pragma unroll
    for (int c = 0; c < NC; c++) {
        const size_t k = (size_t)c * SSTATE + idx;
        float oh = hend[k];
        float oA = Aprod[k];
        hend[k] = carry;
        carry = fmaf(oA, carry, oh);
    }
}

__global__ __launch_bounds__(256)
void scan_phase3(const ushort_t* __restrict__ dtmb,
                 const float* __restrict__ xdbl,
                 const ushort_t* __restrict__ xcb,
                 const float* __restrict__ A_log,
                 const float* __restrict__ Dp,
                 const ushort_t* __restrict__ gz,
                 const float* __restrict__ hinit,
                 ushort_t* __restrict__ yb)
{
    __shared__ float Bs[CL][16];
    __shared__ float Cs[CL][16];
    const int tid = threadIdx.x;
    const int d = blockIdx.x * 256 + tid;
    const int c = blockIdx.y;
    const int t0 = c * CL;

    {
        int r = tid & 127;
        int t = r >> 2, n = (r * 4) & 15;
        const float* src = &xdbl[(size_t)(t0 + t) * XCOLS + DTRANK + ((tid < 128) ? 0 : DSTATE) + n];
        float4 v = *(const float4*)src;
        float* dst = (tid < 128) ? &Bs[t][n] : &Cs[t][n];
        dst[0] = v.x; dst[1] = v.y; dst[2] = v.z; dst[3] = v.w;
    }

    float a[16];
#pragma unroll
    for (int q = 0; q < 4; q++) {
        f32x4 v = *(const f32x4*)&A_log[(size_t)d * DSTATE + q * 4];
#pragma unroll
        for (int j = 0; j < 4; j++) a[q * 4 + j] = -__expf(v[j]);
    }
    const float Dv = Dp[d];
    float h[16];
#pragma unroll
    for (int n = 0; n < 16; n++)
        h[n] = hinit[(size_t)c * SSTATE + (size_t)n * DINNER + d];

    __syncthreads();

    float dtv = bf2f(dtmb[(size_t)t0 * DINNER + d]);
    float xv  = bf2f(xcb[(size_t)t0 * DINNER + d]);
    for (int tt = 0; tt < CL; tt++) {
        const int t = t0 + tt;
        int tn_ = t0 + ((tt + 1 < CL) ? tt + 1 : tt);
        float dtv_n = bf2f(dtmb[(size_t)tn_ * DINNER + d]);
        float xv_n  = bf2f(xcb[(size_t)tn_ * DINNER + d]);
        float gzv   = bf2f(gz[(size_t)t * DINNER + d]);

        f32x4 Bq[4], Cq[4];
#pragma unroll
        for (int q = 0; q < 4; q++) {
            Bq[q] = *(const f32x4*)&Bs[tt][q * 4];
            Cq[q] = *(const f32x4*)&Cs[tt][q * 4];
        }
        float dtx = dtv * xv;
        float y = 0.f;
#pragma unroll
        for (int n = 0; n < 16; n++) {
            float e = __expf(dtv * a[n]);
            h[n] = fmaf(e, h[n], dtx * Bq[n >> 2][n & 3]);
            y = fmaf(h[n], Cq[n >> 2][n & 3], y);
        }
        yb[(size_t)t * DINNER + d] = f2bf((y + Dv * xv) * gzv);
        dtv = dtv_n; xv = xv_n;
    }
}

// ---------------------------------------------------------------------------
extern "C" void kernel_launch(void* const* d_in, const int* in_sizes, int n_in,
                              void* d_out, int out_size, void* d_ws, size_t ws_size,
                              hipStream_t stream)
{
    const float* x      = (const float*)d_in[0];
    const float* W_in   = (const float*)d_in[1];
    const float* conv_w = (const float*)d_in[2];
    const float* conv_b = (const float*)d_in[3];
    const float* W_x    = (const float*)d_in[4];
    const float* W_dt   = (const float*)d_in[5];
    const float* b_dt   = (const float*)d_in[6];
    const float* A_log  = (const float*)d_in[7];
    const float* D_par  = (const float*)d_in[8];
    const float* W_out  = (const float*)d_in[9];
    float* out = (float*)d_out;
    float* ws  = (float*)d_ws;

    // fp32 region
    float* xdbl  = ws;                                    // 196608
    float* Aprod = xdbl + (size_t)LSEQ * XCOLS;           // 2M
    float* hend  = Aprod + (size_t)NC * SSTATE;           // 2M
    // bf16 region
    ushort_t* xb   = (ushort_t*)(hend + (size_t)NC * SSTATE); // 2M  (x cast)
    ushort_t* Wib  = xb   + (size_t)LSEQ * DMODEL;            // 4M  (W_in)
    ushort_t* Wob  = Wib  + (size_t)(2*DINNER) * DMODEL;      // 2M  (W_out)
    ushort_t* Wxb  = Wob  + (size_t)DMODEL * DINNER;          // 196608
    ushort_t* Wdtb = Wxb  + (size_t)XCOLS * DINNER;           // 131072
    ushort_t* xinb = Wdtb + (size_t)DINNER * DTRANK;          // 4M  (pre-conv x)
    ushort_t* gz   = xinb + (size_t)LSEQ * DINNER;            // 4M  (silu(z))
    ushort_t* xcb  = gz   + (size_t)LSEQ * DINNER;            // 4M  (x_conv)
    ushort_t* dtmb = xcb  + (size_t)LSEQ * DINNER;            // 4M  (dt)
    ushort_t* yb   = dtmb + (size_t)LSEQ * DINNER;            // 4M  (y)
    // out_proj SK2 fp32 partials: 2 x 8 MB over xcb+dtmb (dead after phase3).
    float* outp = (float*)xcb;

    // 0. fused casts to bf16 (x, W_in, W_out, W_x, W_dt) + zero xdbl
    {
        int c0 = LSEQ * DMODEL, c1 = 2 * DINNER * DMODEL, c2 = DMODEL * DINNER;
        int c3 = XCOLS * DINNER, c4 = DINNER * DTRANK;
        int cz = LSEQ * XCOLS;
        int total = c0 + c1 + c2 + c3 + c4 + cz;
        hipLaunchKernelGGL(cast6_kernel, dim3((total / 8 + 255) / 256), dim3(256), 0, stream,
                           x, xb, c0, W_in, Wib, c1, W_out, Wob, c2,
                           W_x, Wxb, c3, W_dt, Wdtb, c4, xdbl, cz);
    }

    // 1. in_proj (2048 x 4096), fused epilogue: x-half -> xinb, z-half -> gz
    hipLaunchKernelGGL((gemm_bf16<1,1>), dim3(LSEQ/128, (2*DINNER)/128), dim3(256), 0, stream,
                       xb, Wib, (float*)nullptr, xinb, gz, LSEQ, 2*DINNER, DMODEL, (size_t)0);

    // 2. depthwise conv + SiLU (bf16, vectorized 8 ch/thread)
    hipLaunchKernelGGL(conv_silu_kernel, dim3((LSEQ*DINNER/8)/256), dim3(256), 0, stream,
                       xinb, conv_w, conv_b, xcb);

    // 3. x_dbl = xc @ W_x^T  (2048 x 96), direct-fragment MFMA, split-K=16
    hipLaunchKernelGGL(gemm_xdbl, dim3(LSEQ/128, 1, 16), dim3(256), 0, stream,
                       xcb, Wxb, xdbl);

    // 4. dt = softplus(x_dbl[:, :64] @ W_dt^T + b_dt) -> bf16
    hipLaunchKernelGGL(gemm_dt, dim3(LSEQ/128, DINNER/128), dim3(256), 0, stream,
                       xdbl, Wdtb, b_dt, dtmb);

    // 5. chunked parallel scan, CL=32; phase2 64-thread blocks (512 blocks)
    hipLaunchKernelGGL(scan_phase1, dim3(DINNER/256, NC), dim3(256), 0, stream,
                       dtmb, xdbl, xcb, A_log, Aprod, hend);
    hipLaunchKernelGGL(scan_phase2, dim3(SSTATE/64), dim3(64), 0, stream,
                       Aprod, hend);
    hipLaunchKernelGGL(scan_phase3, dim3(DINNER/256, NC), dim3(256), 0, stream,
                       dtmb, xdbl, xcb, A_log, D_par, gz, hend, yb);

    // 6. out = y @ W_out^T  (2048 x 1024): SK2 partials + add2
    hipLaunchKernelGGL((gemm_bf16<0,2>), dim3(LSEQ/128, DMODEL/128, 2), dim3(256), 0, stream,
                       yb, Wob, outp, (ushort_t*)nullptr, (ushort_t*)nullptr,
                       LSEQ, DMODEL, DINNER, (size_t)(LSEQ*DMODEL));
    hipLaunchKernelGGL(add2_kernel, dim3((LSEQ*DMODEL/4)/256), dim3(256), 0, stream,
                       outp, outp + (size_t)LSEQ*DMODEL, out, LSEQ*DMODEL);
}